// Round 1
// baseline (891.599 us; speedup 1.0000x reference)
//
#include <hip/hip_runtime.h>

// Problem constants (fixed by the reference's shapes)
#define BB 8     // batch
#define FF 16    // node feature dim
#define MM 32    // MLP hidden dim
#define TF 32    // 2*FF (edge input dim)
#define ROW 40   // padded LDS row stride in floats (16B aligned, 2-way bank alias only)

__device__ __forceinline__ float silu_f(float x) {
    return x / (1.0f + __expf(-x));
}

// One dense step: acc[j] += sum_k a[k] * Wp[k*rstride + j], j=0..3.
// Wp already includes the output-column offset for this lane.
__device__ __forceinline__ float4 dense32(const float* __restrict__ Wp, int rstride,
                                          const float a[TF], float4 acc) {
#pragma unroll
    for (int k = 0; k < TF; ++k) {
        const float4 wv = *(const float4*)(Wp + k * rstride);
        acc.x += a[k] * wv.x;
        acc.y += a[k] * wv.y;
        acc.z += a[k] * wv.z;
        acc.w += a[k] * wv.w;
    }
    return acc;
}

__device__ __forceinline__ void load_row(const float* arow, float a[TF]) {
#pragma unroll
    for (int c = 0; c < 8; ++c) {
        const float4 t = *(const float4*)(arow + 4 * c);
        a[4 * c + 0] = t.x;
        a[4 * c + 1] = t.y;
        a[4 * c + 2] = t.z;
        a[4 * c + 3] = t.w;
    }
}

// One wave per edge; 4 waves (4 edges) per 256-thread block. Last block = fixed edge.
// Lane decomposition: lane = b*8 + lg; lane computes y[b][lg*4 .. lg*4+3].
// Wave-synchronous LDS (per-wave slab, in-order DS pipe, no __syncthreads needed).
extern "C" __global__ void __launch_bounds__(256) gnn_edge_kernel(
    const float* __restrict__ x_in, float* __restrict__ x_out,
    const float* __restrict__ Wi0, const float* __restrict__ Wih,
    const float* __restrict__ Wiout, const float* __restrict__ bi0,
    const float* __restrict__ bih, const float* __restrict__ biout,
    const float* __restrict__ Wf0, const float* __restrict__ Wfh,
    const float* __restrict__ Wfout, const float* __restrict__ bf0,
    const float* __restrict__ bfh, const float* __restrict__ bfout,
    const int* __restrict__ src, const int* __restrict__ dst,
    int P, int E, int H,
    long in_ns, long in_bs,     // input strides in floats: node, batch
    long out_ns, long out_bs)   // output strides in floats: node, batch
{
    __shared__ float act[4][BB * ROW];

    const int w    = threadIdx.x >> 6;
    const int lane = threadIdx.x & 63;
    const int b    = lane >> 3;
    const int lg   = lane & 7;
    const int cg   = lg & 3;

    const bool isFixed = (blockIdx.x == (int)gridDim.x - 1);
    if (isFixed && w != 0) return;

    int p, nd, ns;
    const float *W0p, *Whp, *Woutp, *b0p, *bhp, *boutp;
    long whstride, bhstride;
    if (isFixed) {
        W0p = Wf0; Whp = Wfh; Woutp = Wfout;
        b0p = bf0; bhp = bfh; boutp = bfout;
        whstride = (long)(MM * MM);
        bhstride = (long)MM;
        nd = dst[E - 1];
        ns = src[E - 1];
    } else {
        p = blockIdx.x * 4 + w;
        if (p >= P) return;
        W0p   = Wi0   + (long)p * (TF * MM);
        Whp   = Wih   + (long)p * (MM * MM);
        Woutp = Wiout + (long)p * (MM * FF);
        b0p   = bi0   + (long)p * MM;
        bhp   = bih   + (long)p * MM;
        boutp = biout + (long)p * FF;
        whstride = (long)P * (MM * MM);
        bhstride = (long)P * MM;
        nd = dst[p];
        ns = src[p];
    }

    float* arow = &act[w][b * ROW];

    // ---- gather: build e[b] = [x[nd][b][:] | x[ns][b][:]] in LDS ----
    {
        const int   gnode = (lg < 4) ? nd : ns;
        const float* gp = x_in + (long)gnode * in_ns + (long)b * in_bs + cg * 4;
        const float4 g = *(const float4*)gp;
        *(float4*)(arow + ((lg < 4) ? 0 : FF) + cg * 4) = g;
    }

    float a[TF];
    float4 r;

    // ---- stage 1: [2F] -> [M], SiLU ----
    load_row(arow, a);
    r = dense32(W0p + lg * 4, MM, a, *(const float4*)(b0p + lg * 4));
    r.x = silu_f(r.x); r.y = silu_f(r.y); r.z = silu_f(r.z); r.w = silu_f(r.w);
    *(float4*)(arow + lg * 4) = r;

    // ---- hidden stages: [M] -> [M], SiLU ----
    for (int i = 0; i < H; ++i) {
        load_row(arow, a);
        r = dense32(Whp + (long)i * whstride + lg * 4, MM, a,
                    *(const float4*)(bhp + (long)i * bhstride + lg * 4));
        r.x = silu_f(r.x); r.y = silu_f(r.y); r.z = silu_f(r.z); r.w = silu_f(r.w);
        *(float4*)(arow + lg * 4) = r;
    }

    // ---- output stage: [M] -> [F] (lanes lg>=4 compute duplicate chunks) ----
    load_row(arow, a);
    r = dense32(Woutp + cg * 4, FF, a, *(const float4*)(boutp + cg * 4));

    // ---- scatter: lg<4 -> +eff to dst node; lg>=4 -> -eff to src node ----
    const bool pos = (lg < 4);
    if (isFixed && !pos) return;   // fixed edge contributes only +fx to its dst
    const int   node = pos ? nd : ns;
    const float s    = pos ? 1.0f : -1.0f;
    float* op = x_out + (long)node * out_ns + (long)b * out_bs + cg * 4;
    atomicAdd(op + 0, s * r.x);
    atomicAdd(op + 1, s * r.y);
    atomicAdd(op + 2, s * r.z);
    atomicAdd(op + 3, s * r.w);
}

extern "C" void kernel_launch(void* const* d_in, const int* in_sizes, int n_in,
                              void* d_out, int out_size, void* d_ws, size_t ws_size,
                              hipStream_t stream)
{
    const float* h     = (const float*)d_in[0];
    const float* Wi0   = (const float*)d_in[1];
    const float* Wih   = (const float*)d_in[2];
    const float* Wiout = (const float*)d_in[3];
    const float* bi0   = (const float*)d_in[4];
    const float* bih   = (const float*)d_in[5];
    const float* biout = (const float*)d_in[6];
    const float* Wf0   = (const float*)d_in[7];
    const float* Wfh   = (const float*)d_in[8];
    const float* Wfout = (const float*)d_in[9];
    const float* bf0   = (const float*)d_in[10];
    const float* bfh   = (const float*)d_in[11];
    const float* bfout = (const float*)d_in[12];
    const int*   src   = (const int*)d_in[13];
    const int*   dst   = (const int*)d_in[14];

    const int E = in_sizes[13];
    const int P = (E - 1) / 2;
    const int N = in_sizes[0] / (BB * FF);
    const int L = (int)((long)in_sizes[1] / ((long)P * TF * MM));
    const int H = (int)((long)in_sizes[2] / ((long)L * P * MM * MM));

    float* ws0 = (float*)d_ws;
    float* ws1 = ws0 + (long)N * BB * FF;

    const int blocksE = (P + 3) / 4;
    dim3 grid(blocksE + 1), block(256);

    for (int l = 0; l < L; ++l) {
        const float* xin;
        long ins_n, ins_b;
        if (l == 0) { xin = h; ins_n = FF; ins_b = (long)N * FF; }          // h is [B,N,F]
        else        { xin = (l % 2 == 1) ? ws0 : ws1; ins_n = BB * FF; ins_b = FF; } // ws is [N,B,F]

        float* xout;
        long outs_n, outs_b;
        if (l == L - 1) { xout = (float*)d_out; outs_n = FF; outs_b = (long)N * FF; } // out [B,N,F]
        else            { xout = (l % 2 == 0) ? ws0 : ws1; outs_n = BB * FF; outs_b = FF; }

        hipMemsetAsync(xout, 0, (size_t)N * BB * FF * sizeof(float), stream);

        gnn_edge_kernel<<<grid, block, 0, stream>>>(
            xin, xout,
            Wi0   + (long)l * P * TF * MM,
            Wih   + (long)l * H * P * MM * MM,
            Wiout + (long)l * P * MM * FF,
            bi0   + (long)l * P * MM,
            bih   + (long)l * H * P * MM,
            biout + (long)l * P * FF,
            Wf0   + (long)l * TF * MM,
            Wfh   + (long)l * H * MM * MM,
            Wfout + (long)l * MM * FF,
            bf0   + (long)l * MM,
            bfh   + (long)l * H * MM,
            bfout + (long)l * FF,
            src, dst, P, E, H,
            ins_n, ins_b, outs_n, outs_b);
    }
}